// Round 9
// baseline (289.795 us; speedup 1.0000x reference)
//
#include <hip/hip_runtime.h>
#include <hip/hip_bf16.h>
#include <cstdint>

#define NHEAD 16
#define ORDERS 4

typedef short short8 __attribute__((ext_vector_type(8)));
typedef float f32x4 __attribute__((ext_vector_type(4)));

__device__ __forceinline__ unsigned short f32_to_bf16_rtn(float f) {
  union { float f; unsigned u; } v; v.f = f;
  unsigned r = v.u + 0x7FFFu + ((v.u >> 16) & 1u);
  return (unsigned short)(r >> 16);
}

// packed f32x2 -> bf16x2 RNE (v_cvt_pk_bf16_f32); .x lands in low 16 bits
__device__ __forceinline__ unsigned pack2(float lo, float hi) {
  __hip_bfloat162 h = __float22bfloat162_rn(float2{lo, hi});
  return *reinterpret_cast<unsigned*>(&h);
}

typedef __attribute__((address_space(1))) void gvoid;
typedef __attribute__((address_space(3))) void svoid;
__device__ __forceinline__ void gload_lds16(const void* g, void* l) {
  // LDS dest = base + lane*16 (wave-uniform base); global src is per-lane
  __builtin_amdgcn_global_load_lds((gvoid*)g, (svoid*)l, 16, 0, 0);
}

// ====== weff kernel: block (h, 64-col chunk c) computes M_h then W_eff ======
__global__ __launch_bounds__(256) void weff_kernel(
    const float* __restrict__ A, const float* __restrict__ t_ptr,
    const float* __restrict__ W, const float* __restrict__ bvec,
    unsigned short* __restrict__ Weff, float* __restrict__ beff) {
  __shared__ float Ah[64 * 65];  // reused as Mh (stride 64) after the orders
  __shared__ float T0[64 * 64];
  __shared__ float T1[64 * 64];

  const int tid = threadIdx.x;
  const int h = blockIdx.x >> 4;
  const int c = blockIdx.x & 15;
  const int d = tid & 63;
  const int ig = tid >> 6;

  float wreg[16];
  #pragma unroll
  for (int r = 0; r < 16; ++r)
    wreg[r] = W[(size_t)(h * 64 + ig * 16 + r) * 1024 + c * 64 + d];

  const float t = t_ptr[0];
  const int i = tid >> 2;
  const int jq = (tid & 3) << 4;

  for (int r = 0; r < 16; ++r) {
    int idx = tid + 256 * r;
    Ah[(idx >> 6) * 65 + (idx & 63)] = A[h * 4096 + idx];
  }
  float ms[16];
  #pragma unroll
  for (int cc = 0; cc < 16; ++cc) {
    float e = (i == jq + cc) ? 1.0f : 0.0f;
    T0[i * 64 + jq + cc] = e;
    ms[cc] = e;
  }
  __syncthreads();

  float* Tc = T0;
  float* Tn = T1;
  for (int k = 1; k <= ORDERS; ++k) {
    float scale = t / (float)k;
    float acc[16];
    #pragma unroll
    for (int cc = 0; cc < 16; ++cc) acc[cc] = 0.f;
    for (int l = 0; l < 64; ++l) {
      float a = Ah[i * 65 + l];
      float4 t0 = *(const float4*)&Tc[l * 64 + jq];
      float4 t1 = *(const float4*)&Tc[l * 64 + jq + 4];
      float4 t2 = *(const float4*)&Tc[l * 64 + jq + 8];
      float4 t3 = *(const float4*)&Tc[l * 64 + jq + 12];
      acc[0] += a * t0.x;  acc[1] += a * t0.y;  acc[2] += a * t0.z;  acc[3] += a * t0.w;
      acc[4] += a * t1.x;  acc[5] += a * t1.y;  acc[6] += a * t1.z;  acc[7] += a * t1.w;
      acc[8] += a * t2.x;  acc[9] += a * t2.y;  acc[10] += a * t2.z; acc[11] += a * t2.w;
      acc[12] += a * t3.x; acc[13] += a * t3.y; acc[14] += a * t3.z; acc[15] += a * t3.w;
    }
    #pragma unroll
    for (int cc = 0; cc < 16; ++cc) { acc[cc] *= scale; ms[cc] += acc[cc]; }
    #pragma unroll
    for (int u = 0; u < 4; ++u) {
      float4 v = {acc[u * 4], acc[u * 4 + 1], acc[u * 4 + 2], acc[u * 4 + 3]};
      *(float4*)&Tn[i * 64 + jq + u * 4] = v;
    }
    __syncthreads();
    float* tmp = Tc; Tc = Tn; Tn = tmp;
  }

  float* Mh = Ah;
  #pragma unroll
  for (int u = 0; u < 4; ++u) {
    float4 v = {ms[u * 4], ms[u * 4 + 1], ms[u * 4 + 2], ms[u * 4 + 3]};
    *(float4*)&Mh[i * 64 + jq + u * 4] = v;
  }
  float* Wc = T0;
  #pragma unroll
  for (int r = 0; r < 16; ++r) Wc[(ig * 16 + r) * 64 + d] = wreg[r];
  __syncthreads();

  #pragma unroll
  for (int ii = 0; ii < 16; ++ii) {
    int i2 = ig * 16 + ii;
    float acc = 0.f;
    #pragma unroll
    for (int j = 0; j < 64; ++j) acc += Mh[i2 * 64 + j] * Wc[j * 64 + d];
    Weff[(size_t)(h * 64 + i2) * 1024 + c * 64 + d] = f32_to_bf16_rtn(acc);
  }
  if (c == 0 && tid < 64) {
    float acc = 0.f;
    for (int j = 0; j < 64; ++j) acc += Mh[tid * 64 + j] * bvec[h * 64 + j];
    beff[h * 64 + tid] = acc;
  }
}

// ======= GEMM: out = bf16(X) @ Weff^T + beff; A direct f32->reg->cvt =========
// 128x128x64 tile, 4 waves. A: per-lane fragment loads straight from X (f32,
// coalesced 16 rows x 64B), cvt_pk to bf16 in-register -> NO LDS for A, no
// convert prepass. B: gload_lds w16 + XOR-swizzle dbuf (R4-proven). Counted
// vmcnt: per iter drain B(t) only [vmcnt(20)], then A(t+1) after MFMA
// [vmcnt(4)]; loads never drain to 0 mid-loop. 2 barriers/iter.
#define CSTR 132  // padded f32 stride for epilogue staging

__global__ __launch_bounds__(256, 2) void gemm_kernel(
    const float* __restrict__ X, const unsigned short* __restrict__ Wf,
    const float* __restrict__ beff, float* __restrict__ Out) {
  __shared__ __align__(16) unsigned short Bs[2 * 8192];  // 32 KB (B dbuf only)

  const int wg = blockIdx.x;
  const int swz = (wg & 7) * 256 + (wg >> 3);  // 2048 % 8 == 0: bijective
  const int R = (swz >> 3) * 128;
  const int C = (swz & 7) * 128;

  const int tid = threadIdx.x;
  const int lane = tid & 63;
  const int wave = tid >> 6;
  const int wm = wave >> 1;
  const int wn = wave & 1;
  const int frow = lane & 15;
  const int fkg = lane >> 4;

  f32x4 acc[4][4];
  #pragma unroll
  for (int mi = 0; mi < 4; ++mi)
    #pragma unroll
    for (int ni = 0; ni < 4; ++ni) acc[mi][ni] = (f32x4){0.f, 0.f, 0.f, 0.f};

  // ---- B staging (unchanged, proven): pre-swizzled source, linear LDS dest
  const int lr = lane >> 3;
  const int lc = lane & 7;
  const int scol = ((lc ^ lr) << 3);
  const unsigned short* Bsrc = Wf + (size_t)(C + wave * 32 + lr) * 1024 + scol;
  auto stageB = [&](int kt) {  // 4 gload_lds per wave
    char* Bd = (char*)(Bs + (kt & 1) * 8192) + wave * 4096;
    const int kb = kt * 64;
    #pragma unroll
    for (int i = 0; i < 4; ++i)
      gload_lds16(Bsrc + (size_t)(i * 8) * 1024 + kb, Bd + i * 1024);
  };

  // ---- A direct per-lane fragment loads: row = R+wm*64+mi*16+frow,
  //      cols = kt*64 + kk*32 + fkg*8 .. +8 (8 f32 = 2 float4 per frag)
  const float* Abase = X + (size_t)(R + wm * 64 + frow) * 1024 + fkg * 8;
  float4 fA[16];  // single set, static indexing
  auto loadA = [&](int kt) {  // 16 dwordx4 per lane
    #pragma unroll
    for (int mi = 0; mi < 4; ++mi)
      #pragma unroll
      for (int kk = 0; kk < 2; ++kk) {
        const float* p = Abase + (size_t)(mi * 16) * 1024 + kt * 64 + kk * 32;
        fA[(mi * 2 + kk) * 2] = *(const float4*)p;
        fA[(mi * 2 + kk) * 2 + 1] = *(const float4*)(p + 4);
      }
  };
  short8 afr[4][2];
  auto cvtA = [&]() {  // 32 cvt_pk
    #pragma unroll
    for (int mi = 0; mi < 4; ++mi)
      #pragma unroll
      for (int kk = 0; kk < 2; ++kk) {
        int f = (mi * 2 + kk) * 2;
        union { unsigned u[4]; short8 s; } cv;
        cv.u[0] = pack2(fA[f].x, fA[f].y);
        cv.u[1] = pack2(fA[f].z, fA[f].w);
        cv.u[2] = pack2(fA[f + 1].x, fA[f + 1].y);
        cv.u[3] = pack2(fA[f + 1].z, fA[f + 1].w);
        afr[mi][kk] = cv.s;
      }
  };

  // Prologue: A(0) + B(0) in flight; drain A(0) only (B(0) stays in flight).
  loadA(0);
  stageB(0);
  __builtin_amdgcn_sched_barrier(0);
  asm volatile("s_waitcnt vmcnt(4)" ::: "memory");
  __builtin_amdgcn_sched_barrier(0);

  for (int t = 0; t < 16; ++t) {
    cvtA();  // A(t) -> afr (regs guaranteed by prior vmcnt(4))
    if (t + 1 < 16) {
      loadA(t + 1);   // reuse fA regs (WAR on registers, in-order per reg)
      stageB(t + 1);  // other buf; WAR protected by prior end-of-iter barrier
    }
    __builtin_amdgcn_sched_barrier(0);
    // Drain B(t): outstanding = B(t)4 + A(t+1)16 + B(t+1)4 -> keep newest 20.
    if (t < 15) asm volatile("s_waitcnt vmcnt(20)" ::: "memory");
    else        asm volatile("s_waitcnt vmcnt(0)"  ::: "memory");
    __builtin_amdgcn_sched_barrier(0);
    __builtin_amdgcn_s_barrier();  // B(t) visible to all waves

    const unsigned short* B = Bs + (t & 1) * 8192;
    short8 bfr[4][2];
    #pragma unroll
    for (int ni = 0; ni < 4; ++ni) {
      int br = wn * 64 + ni * 16 + frow;
      #pragma unroll
      for (int kk = 0; kk < 2; ++kk) {
        int slot = (kk * 4 + fkg) ^ (br & 7);
        bfr[ni][kk] = *(const short8*)&B[br * 64 + slot * 8];
      }
    }
    asm volatile("s_waitcnt lgkmcnt(0)" ::: "memory");
    __builtin_amdgcn_sched_barrier(0);

    __builtin_amdgcn_s_setprio(1);
    #pragma unroll
    for (int mi = 0; mi < 4; ++mi)
      #pragma unroll
      for (int ni = 0; ni < 4; ++ni)
        #pragma unroll
        for (int kk = 0; kk < 2; ++kk)
          acc[mi][ni] = __builtin_amdgcn_mfma_f32_16x16x32_bf16(
              afr[mi][kk], bfr[ni][kk], acc[mi][ni], 0, 0, 0);
    __builtin_amdgcn_s_setprio(0);

    // Drain A(t+1) (leaves B(t+1) 4 in flight across the barrier).
    if (t + 1 < 16) asm volatile("s_waitcnt vmcnt(4)" ::: "memory");
    __builtin_amdgcn_sched_barrier(0);
    __builtin_amdgcn_s_barrier();  // all ds_reads of buf(t&1) done -> reusable
  }
  __syncthreads();

  // Epilogue: stage 32x128 f32 tile through LDS -> full-line float4 stores
  float* Cs = (float*)Bs;  // 32*132*4 = 16896 B <= 32 KB
  const int c4 = (tid & 31) << 2;
  float4 bb = *(const float4*)&beff[C + c4];
  #pragma unroll
  for (int mi = 0; mi < 4; ++mi) {
    #pragma unroll
    for (int ni = 0; ni < 4; ++ni) {
      int col = wn * 64 + ni * 16 + frow;
      #pragma unroll
      for (int reg = 0; reg < 4; ++reg)
        Cs[(wm * 16 + fkg * 4 + reg) * CSTR + col] = acc[mi][ni][reg];
    }
    __syncthreads();
    #pragma unroll
    for (int it = 0; it < 4; ++it) {
      int rloc = it * 8 + (tid >> 5);
      float4 v = *(const float4*)&Cs[rloc * CSTR + c4];
      v.x += bb.x; v.y += bb.y; v.z += bb.z; v.w += bb.w;
      int grow = R + (rloc >> 4) * 64 + mi * 16 + (rloc & 15);
      *(float4*)(Out + (size_t)grow * 1024 + C + c4) = v;
    }
    __syncthreads();
  }
}

extern "C" void kernel_launch(void* const* d_in, const int* in_sizes, int n_in,
                              void* d_out, int out_size, void* d_ws, size_t ws_size,
                              hipStream_t stream) {
  const float* x = (const float*)d_in[0];
  const float* t = (const float*)d_in[1];
  const float* W = (const float*)d_in[2];
  const float* b = (const float*)d_in[3];
  const float* A = (const float*)d_in[4];
  float* out = (float*)d_out;

  char* ws = (char*)d_ws;
  unsigned short* Weff = (unsigned short*)ws;  // 2 MB @ 0
  float* beff = (float*)(ws + (2 << 20));      // 4 KB @ 2 MB

  weff_kernel<<<256, 256, 0, stream>>>(A, t, W, b, Weff, beff);
  gemm_kernel<<<2048, 256, 0, stream>>>(x, Weff, beff, out);
}